// Round 20
// baseline (108.072 us; speedup 1.0000x reference)
//
#include <hip/hip_runtime.h>
#include <hip/hip_bf16.h>

#define N_V 6890
#define NVPAD 6912    // padded vertex count
#define N_J 24
#define NREAL 20670   // N_V*3
#define NPROWS 27648  // NVPAD*4 padded GEMM rows (n' = 4v+c, c=3 dummy)
#define KDIM 224      // 207 lrot + 10 beta + 1 template + 6 zero pad
#define FB 32         // batches per fused block
#define FV 64         // vertices per fused block -> 256 n' rows
#define SHP 260       // LDS pitch (ushorts) for sH row ([64 slots][4] + 4 pad)
#define NXT 108       // vertex tiles (6912/64)

typedef __attribute__((ext_vector_type(8))) short bf16x8;
typedef __attribute__((ext_vector_type(4))) float f32x4;

__constant__ int c_par[23] = {0,0,0,1,2,3,4,5,6,7,8,9,9,9,12,13,14,16,17,18,19,20,21};

static __device__ __forceinline__ unsigned short f2bf(float f) {
    unsigned int u = __float_as_uint(f);
    unsigned int r = (u + 0x7fffu + ((u >> 16) & 1u)) >> 16;
    return (unsigned short)r;
}
// fast pack: round-half-up (bias <= 0.5 ulp, fine at our tolerance)
static __device__ __forceinline__ unsigned int pkbf(float a, float b) {
    return ((__float_as_uint(a) + 0x8000u) >> 16) |
           ((__float_as_uint(b) + 0x8000u) & 0xffff0000u);
}
// frag-linear index for a [rows16][K] bf16 matrix: chunk(row16,ks) of 512, lane l at l*8
static __device__ __forceinline__ size_t fragidx(int r, int k) {
    return ((size_t)((r >> 4) * 7 + (k >> 5)) << 9) +
           ((size_t)((r & 15) + (((k >> 3) & 3) << 4)) << 3) + (k & 7);
}

// ws layout:
//   floats: partial[24*8*33]=6336 @0
//   ushort region @ float ofs 7128:
//     Amf  [64][7][512]   @0        (Amat frag-linear)
//     Bpf  [1728][7][512] @229376   (frag-linear)
//     Gbf  [1024][16][32] @6422528
//     Wbf  [6912][32]     @6946816
#define WS_PARTIAL 0
#define WS_USHORT  7128
#define U_AMF  0
#define U_BPF  229376
#define U_GBF  6422528
#define U_WBF  6946816

#define JREG_BLOCKS 192                  // 24 joints x 8 chunks
#define BPF_BLOCKS  (NPROWS / 16)        // 1728
#define WBF_BLOCKS  (NVPAD * 32 / 256)   // 864

static __device__ __forceinline__ float bval(const float* pd, const float* sd,
                                             const float* vt, int nc, int k) {
    if (k < 207)  return pd[(size_t)nc * 207 + k];
    if (k < 217)  return sd[(size_t)nc * 10 + (k - 207)];
    if (k == 217) return vt[nc];
    return 0.f;
}

// ---------------- Kernel 1: merged prep (jreg partials | Bpf via LDS tile | Wbf) ----
__global__ __launch_bounds__(256)
void k_pre(const float* __restrict__ Jreg,
           const float* __restrict__ shapedirs,
           const float* __restrict__ v_template,
           const float* __restrict__ posedirs,
           const float* __restrict__ weights,
           float* __restrict__ partial,
           unsigned short* __restrict__ Bpf,
           unsigned short* __restrict__ Wbf) {
    const int bid = blockIdx.x;
    const int tid = threadIdx.x;

    if (bid < JREG_BLOCKS) {
        // ---- stage-1 J_regressor partial: joint j, vertex chunk ----
        const int j = bid >> 3, chunk = bid & 7;
        const int per = (N_V + 7) / 8;
        const int v0 = chunk * per;
        const int v1 = (v0 + per < N_V) ? (v0 + per) : N_V;
        float acc[33];
#pragma unroll
        for (int k = 0; k < 33; ++k) acc[k] = 0.f;
        for (int v = v0 + tid; v < v1; v += 256) {
            const float w = Jreg[j * N_V + v];
            const float* sd = shapedirs + (size_t)v * 30;
#pragma unroll
            for (int k = 0; k < 30; ++k) acc[k] += w * sd[k];
            acc[30] += w * v_template[v * 3 + 0];
            acc[31] += w * v_template[v * 3 + 1];
            acc[32] += w * v_template[v * 3 + 2];
        }
#pragma unroll
        for (int k = 0; k < 33; ++k) {
            float x = acc[k];
            for (int off = 32; off > 0; off >>= 1) x += __shfl_down(x, off);
            acc[k] = x;
        }
        __shared__ float red[4][33];
        const int wave = tid >> 6, lane = tid & 63;
        if (lane == 0) {
#pragma unroll
            for (int k = 0; k < 33; ++k) red[wave][k] = acc[k];
        }
        __syncthreads();
        if (tid < 33) {
            partial[(j * 8 + chunk) * 33 + tid] =
                red[0][tid] + red[1][tid] + red[2][tid] + red[3][tid];
        }
    } else if (bid < JREG_BLOCKS + BPF_BLOCKS) {
        // ---- Bpf: stage [16][224] f32 tile in LDS, emit frag-linear ----
        // division-free fill: thread = (row = tid>>4, 14 contiguous k)
        __shared__ float tile[16][228];  // pitch 228 to spread banks
        const int r16 = bid - JREG_BLOCKS;
        {
            const int row = tid >> 4;          // 0..15
            const int k0 = (tid & 15) * 14;    // 14 consecutive k
            const int np = r16 * 16 + row;
            const int v = np >> 2, cc = np & 3;
            if (cc < 3 && v < N_V) {
                const int nc = v * 3 + cc;
                const float* pd = posedirs + (size_t)nc * 207;
#pragma unroll
                for (int i = 0; i < 14; ++i) {
                    const int k = k0 + i;
                    float val;
                    if (k < 207)       val = pd[k];
                    else if (k < 217)  val = shapedirs[(size_t)nc * 10 + (k - 207)];
                    else if (k == 217) val = v_template[nc];
                    else               val = 0.f;
                    tile[row][k] = val;
                }
            } else {
#pragma unroll
                for (int i = 0; i < 14; ++i) tile[row][k0 + i] = 0.f;
            }
        }
        __syncthreads();
        const int l = tid >> 2;
        const int row = l & 15;
        const int kblk = (l >> 4) * 8;
        const int e2 = (tid & 3) * 2;
        unsigned short* dst = Bpf + ((size_t)r16 * 7) * 512 + (size_t)tid * 2;
#pragma unroll
        for (int ks = 0; ks < 7; ++ks) {
            const int k = ks * 32 + kblk + e2;
            ushort2 o;
            o.x = f2bf(tile[row][k]);
            o.y = f2bf(tile[row][k + 1]);
            *(ushort2*)(dst + (size_t)ks * 512) = o;
        }
    } else {
        // ---- Wbf[v][32] bf16 zero-padded ----
        const int idx = (bid - JREG_BLOCKS - BPF_BLOCKS) * 256 + tid;
        const int v = idx >> 5, k = idx & 31;
        float val = (v < N_V && k < 24) ? weights[(size_t)v * 24 + k] : 0.f;
        Wbf[idx] = f2bf(val);
    }
}

// ---------------- Kernel 2: joints (8 batches/block): fold + Rodrigues + FK + Amf + Gbf ----
__global__ __launch_bounds__(512)
void k_joints(const float* __restrict__ pose, const float* __restrict__ beta,
              const float* __restrict__ partial,
              unsigned short* __restrict__ Amf,
              unsigned short* __restrict__ Gbf) {
    const int tid = threadIdx.x;
    const int wid = tid >> 6;          // batch-in-block 0..7
    const int j = tid & 63;
    const int b = blockIdx.x * 8 + wid;
    __shared__ float sJS[24][30];
    __shared__ float sJt_[24][3];
    __shared__ float sJ[8][24][3];
    __shared__ float sG[8][24][12];

    // fold stage-2 of the jreg reduction (8-chunk sum), amortized over 8 batches
    for (int idx = tid; idx < 792; idx += 512) {
        const int jj = idx / 33, kk = idx - jj * 33;
        float s = 0.f;
#pragma unroll
        for (int c = 0; c < 8; ++c) s += partial[(jj * 8 + c) * 33 + kk];
        if (kk < 30) sJS[jj][kk] = s;
        else         sJt_[jj][kk - 30] = s;
    }

    // zero-fill ONLY the pad entries of Gbf for this wave's batch
    for (int idx = j; idx < 224; idx += 64) {
        int mn, jj;
        if (idx < 128) { mn = 12 + (idx >> 5); jj = idx & 31; }
        else { const int q = idx - 128; mn = q >> 3; jj = 24 + (q & 7); }
        Gbf[(size_t)b * 512 + mn * 32 + jj] = 0;
    }
    __syncthreads();

    float R[9];
    if (j < 24) {
        const float* bt = beta + b * 10;
#pragma unroll
        for (int c = 0; c < 3; ++c) {
            float s = sJt_[j][c];
#pragma unroll
            for (int t = 0; t < 10; ++t) s += sJS[j][c * 10 + t] * bt[t];
            sJ[wid][j][c] = s;
        }
        const float rx = pose[b * 72 + 3 * j + 0];
        const float ry = pose[b * 72 + 3 * j + 1];
        const float rz = pose[b * 72 + 3 * j + 2];
        const float ang = sqrtf(rx * rx + ry * ry + rz * rz + 1e-8f);
        const float inv = 1.f / ang;
        const float x = rx * inv, y = ry * inv, z = rz * inv;
        const float c = cosf(ang), s = sinf(ang);
        const float ic = 1.f - c;
        R[0] = c + ic * x * x;     R[1] = ic * x * y - s * z; R[2] = ic * x * z + s * y;
        R[3] = ic * x * y + s * z; R[4] = c + ic * y * y;     R[5] = ic * y * z - s * x;
        R[6] = ic * x * z - s * y; R[7] = ic * y * z + s * x; R[8] = c + ic * z * z;
        if (j >= 1) {
            const int kb = (j - 1) * 9;
#pragma unroll
            for (int k = 0; k < 9; ++k)
                Amf[fragidx(b & 15, kb + k) + (size_t)(b >> 4) * 3584] =
                    f2bf(R[k] - ((k == 0 || k == 4 || k == 8) ? 1.f : 0.f));
        }
    } else if (j < 41) {
        const int k = 207 + (j - 24);
        float val = (k < 217) ? beta[b * 10 + (k - 207)] : (k == 217 ? 1.f : 0.f);
        Amf[fragidx(b & 15, k) + (size_t)(b >> 4) * 3584] = f2bf(val);
    }
    __syncthreads();
    if (j < 24) {
        float t0, t1, t2;
        if (j == 0) { t0 = sJ[wid][0][0]; t1 = sJ[wid][0][1]; t2 = sJ[wid][0][2]; }
        else {
            const int p = c_par[j - 1];
            t0 = sJ[wid][j][0] - sJ[wid][p][0];
            t1 = sJ[wid][j][1] - sJ[wid][p][1];
            t2 = sJ[wid][j][2] - sJ[wid][p][2];
        }
        sG[wid][j][0] = R[0]; sG[wid][j][1] = R[1]; sG[wid][j][2]  = R[2]; sG[wid][j][3]  = t0;
        sG[wid][j][4] = R[3]; sG[wid][j][5] = R[4]; sG[wid][j][6]  = R[5]; sG[wid][j][7]  = t1;
        sG[wid][j][8] = R[6]; sG[wid][j][9] = R[7]; sG[wid][j][10] = R[8]; sG[wid][j][11] = t2;
    }
    __syncthreads();
    if (j == 0) {
        for (int i = 1; i < 24; ++i) {
            const int p = c_par[i - 1];
            float P[12], L[12];
#pragma unroll
            for (int k = 0; k < 12; ++k) { P[k] = sG[wid][p][k]; L[k] = sG[wid][i][k]; }
#pragma unroll
            for (int m = 0; m < 3; ++m) {
#pragma unroll
                for (int n = 0; n < 3; ++n)
                    sG[wid][i][m * 4 + n] = P[m * 4] * L[n] + P[m * 4 + 1] * L[4 + n] + P[m * 4 + 2] * L[8 + n];
                sG[wid][i][m * 4 + 3] = P[m * 4] * L[3] + P[m * 4 + 1] * L[7] + P[m * 4 + 2] * L[11] + P[m * 4 + 3];
            }
        }
    }
    __syncthreads();
    if (j < 24) {
        const float jx = sJ[wid][j][0], jy = sJ[wid][j][1], jz = sJ[wid][j][2];
#pragma unroll
        for (int m = 0; m < 3; ++m) {
            const float corr = sG[wid][j][m * 4] * jx + sG[wid][j][m * 4 + 1] * jy + sG[wid][j][m * 4 + 2] * jz;
            Gbf[(size_t)b * 512 + (m * 4 + 0) * 32 + j] = f2bf(sG[wid][j][m * 4 + 0]);
            Gbf[(size_t)b * 512 + (m * 4 + 1) * 32 + j] = f2bf(sG[wid][j][m * 4 + 1]);
            Gbf[(size_t)b * 512 + (m * 4 + 2) * 32 + j] = f2bf(sG[wid][j][m * 4 + 2]);
            Gbf[(size_t)b * 512 + (m * 4 + 3) * 32 + j] = f2bf(sG[wid][j][m * 4 + 3] - corr);
        }
    }
}

// ---------------- Kernel 3: fused pose-GEMM + skinning, FB=32 @ 32 waves/CU ----
// R17 body (refchecked) with __launch_bounds__(512,8): VGPR<=64 budget (R17
// compiled to 40), LDS 16.9KB -> 4 blocks/CU co-resident = 32 waves/CU.
__global__ __launch_bounds__(512, 8)
void k_fused(const unsigned short* __restrict__ Amf,
             const unsigned short* __restrict__ Bpf,
             const unsigned short* __restrict__ Gbf,
             const unsigned short* __restrict__ Wbf,
             float* __restrict__ out) {
    __shared__ unsigned short sH[FB * SHP];   // 16,640 B  ([b][v][4] bf16)
    const int tid = threadIdx.x;
    const int wid = tid >> 6, l = tid & 63;   // wid 0..7
    const int c16 = l & 15, p = l >> 4;

    // bijective XCD swizzle for 3456 blocks: 3456 = 8 x 432
    const int wg = ((blockIdx.x & 7) * 432) + (blockIdx.x >> 3);
    const int xt = wg >> 5;    // vertex tile 0..107
    const int bg = wg & 31;    // batch group 0..31
    const int v0 = xt * FV;
    const int b0 = bg * FB;

    // phase-2 invariant loads issued first (latency hides under phase 1)
    bf16x8 bw[4];
#pragma unroll
    for (int g = 0; g < 4; ++g)
        bw[g] = *(const bf16x8*)&Wbf[(size_t)(v0 + g * 16 + c16) * 32 + p * 8];
    const int bwv = wid * 4;  // wave's local batch base
    const unsigned short* gG = Gbf + (size_t)(b0 + bwv) * 512 + c16 * 32 + p * 8;

    // -------- phase 1: register GEMM, frag-linear operands from global --------
    f32x4 acc[2][2];
#pragma unroll
    for (int i = 0; i < 2; ++i)
#pragma unroll
        for (int j = 0; j < 2; ++j) acc[i][j] = (f32x4){0.f, 0.f, 0.f, 0.f};

    const unsigned short* pbf = Bpf + ((size_t)(xt * 16 + wid * 2) * 7) * 512 + (size_t)l * 8;
    const unsigned short* pam = Amf + ((size_t)(bg * 2) * 7) * 512 + (size_t)l * 8;

#pragma unroll
    for (int ks = 0; ks < 7; ++ks) {
        bf16x8 af[2], bfr[2];
#pragma unroll
        for (int mi = 0; mi < 2; ++mi)
            af[mi] = *(const bf16x8*)(pbf + (size_t)(mi * 7 + ks) * 512);
#pragma unroll
        for (int bj = 0; bj < 2; ++bj)
            bfr[bj] = *(const bf16x8*)(pam + (size_t)(bj * 7 + ks) * 512);
        __builtin_amdgcn_s_setprio(1);
#pragma unroll
        for (int mi = 0; mi < 2; ++mi)
#pragma unroll
            for (int bj = 0; bj < 2; ++bj)
                acc[mi][bj] = __builtin_amdgcn_mfma_f32_16x16x32_bf16(af[mi], bfr[bj], acc[mi][bj], 0, 0, 0);
        __builtin_amdgcn_s_setprio(0);
    }

    // first Gbf chunk issued BEFORE epilogue: latency hides under ds_writes+barrier
    bf16x8 agA[2], agB[2];
#pragma unroll
    for (int j = 0; j < 2; ++j)
        agA[j] = *(const bf16x8*)(gG + (size_t)j * 512);

    // -------- epilogue: acc -> sH (b64 per vertex slot) --------
    {
        const int vbase = wid * 8 + p;
#pragma unroll
        for (int mi = 0; mi < 2; ++mi) {
#pragma unroll
            for (int bj = 0; bj < 2; ++bj) {
                const int vl = vbase + mi * 4;
                const int bl = bj * 16 + c16;
                uint2 u;
                u.x = pkbf(acc[mi][bj][0], acc[mi][bj][1]);
                u.y = pkbf(acc[mi][bj][2], acc[mi][bj][3]);
                *(uint2*)&sH[bl * SHP + vl * 4] = u;
            }
        }
    }
    __syncthreads();

    // second Gbf chunk: latency hides under chunk-A compute
#pragma unroll
    for (int j = 0; j < 2; ++j)
        agB[j] = *(const bf16x8*)(gG + (size_t)(2 + j) * 512);

    // -------- phase 2: skinning, 4 vertex groups per batch --------
    bool st[4];
#pragma unroll
    for (int g = 0; g < 4; ++g)
        st[g] = (v0 + g * 16 + c16 < N_V) && (p < 3);
    float* ob = out + (size_t)(b0 + bwv) * NREAL + (size_t)(v0 + c16) * 3 + p;
    const unsigned short* sh = &sH[bwv * SHP + c16 * 4];

    __builtin_amdgcn_s_setprio(1);
#pragma unroll
    for (int j = 0; j < 2; ++j) {
#pragma unroll
        for (int g = 0; g < 4; ++g) {
            const f32x4 t = __builtin_amdgcn_mfma_f32_16x16x32_bf16(agA[j], bw[g], (f32x4){0.f,0.f,0.f,0.f}, 0, 0, 0);
            const uint2 h = *(const uint2*)(sh + j * SHP + g * 64);
            const float x = __uint_as_float(h.x << 16);
            const float y = __uint_as_float(h.x & 0xffff0000u);
            const float z = __uint_as_float(h.y << 16);
            const float r = t[0] * x + t[1] * y + t[2] * z + t[3];
            if (st[g]) ob[(size_t)j * NREAL + g * 48] = r;
        }
    }
    __builtin_amdgcn_s_setprio(0);
#pragma unroll
    for (int j = 0; j < 2; ++j) {
#pragma unroll
        for (int g = 0; g < 4; ++g) {
            const f32x4 t = __builtin_amdgcn_mfma_f32_16x16x32_bf16(agB[j], bw[g], (f32x4){0.f,0.f,0.f,0.f}, 0, 0, 0);
            const uint2 h = *(const uint2*)(sh + (2 + j) * SHP + g * 64);
            const float x = __uint_as_float(h.x << 16);
            const float y = __uint_as_float(h.x & 0xffff0000u);
            const float z = __uint_as_float(h.y << 16);
            const float r = t[0] * x + t[1] * y + t[2] * z + t[3];
            if (st[g]) ob[(size_t)(2 + j) * NREAL + g * 48] = r;
        }
    }
}

extern "C" void kernel_launch(void* const* d_in, const int* in_sizes, int n_in,
                              void* d_out, int out_size, void* d_ws, size_t ws_size,
                              hipStream_t stream) {
    const float* pose       = (const float*)d_in[0];
    const float* beta       = (const float*)d_in[1];
    const float* shapedirs  = (const float*)d_in[2];
    const float* posedirs   = (const float*)d_in[3];
    const float* v_template = (const float*)d_in[4];
    const float* Jreg       = (const float*)d_in[5];
    const float* weights    = (const float*)d_in[6];
    float* out = (float*)d_out;

    const int B = in_sizes[0] / 72;  // 1024

    float* ws = (float*)d_ws;
    float* partial = ws + WS_PARTIAL;
    unsigned short* ubase = (unsigned short*)(ws + WS_USHORT);
    unsigned short* Amf = ubase + U_AMF;
    unsigned short* Bpf = ubase + U_BPF;
    unsigned short* Gbf = ubase + U_GBF;
    unsigned short* Wbf = ubase + U_WBF;

    k_pre<<<JREG_BLOCKS + BPF_BLOCKS + WBF_BLOCKS, 256, 0, stream>>>(
        Jreg, shapedirs, v_template, posedirs, weights, partial, Bpf, Wbf);
    k_joints<<<B / 8, 512, 0, stream>>>(pose, beta, partial, Amf, Gbf);
    k_fused<<<NXT * (B / FB), 512, 0, stream>>>(Amf, Bpf, Gbf, Wbf, out);
}

// Round 21
// 69.126 us; speedup vs baseline: 1.5634x; 1.5634x over previous
//
#include <hip/hip_runtime.h>
#include <hip/hip_bf16.h>

#define N_V 6890
#define NVPAD 6912    // padded vertex count
#define N_J 24
#define NREAL 20670   // N_V*3
#define NPROWS 27648  // NVPAD*4 padded GEMM rows (n' = 4v+c, c=3 dummy)
#define KDIM 224      // 207 lrot + 10 beta + 1 template + 6 zero pad
#define FB 64         // batches per fused block
#define FV 64         // vertices per fused block -> 256 n' rows
#define SHP 260       // LDS pitch (ushorts) for sH row ([64 slots][4] + 4 pad)
#define NXT 108       // vertex tiles (6912/64)

typedef __attribute__((ext_vector_type(8))) short bf16x8;
typedef __attribute__((ext_vector_type(4))) float f32x4;

__constant__ int c_par[23] = {0,0,0,1,2,3,4,5,6,7,8,9,9,9,12,13,14,16,17,18,19,20,21};

static __device__ __forceinline__ unsigned short f2bf(float f) {
    unsigned int u = __float_as_uint(f);
    unsigned int r = (u + 0x7fffu + ((u >> 16) & 1u)) >> 16;
    return (unsigned short)r;
}
// fast pack: round-half-up (bias <= 0.5 ulp, fine at our tolerance)
static __device__ __forceinline__ unsigned int pkbf(float a, float b) {
    return ((__float_as_uint(a) + 0x8000u) >> 16) |
           ((__float_as_uint(b) + 0x8000u) & 0xffff0000u);
}
// frag-linear index for a [rows16][K] bf16 matrix: chunk(row16,ks) of 512, lane l at l*8
static __device__ __forceinline__ size_t fragidx(int r, int k) {
    return ((size_t)((r >> 4) * 7 + (k >> 5)) << 9) +
           ((size_t)((r & 15) + (((k >> 3) & 3) << 4)) << 3) + (k & 7);
}

// ws layout:
//   floats: partial[24*8*33]=6336 @0
//   ushort region @ float ofs 7128:
//     Amf  [64][7][512]   @0        (Amat frag-linear)
//     Bpf  [1728][7][512] @229376   (frag-linear)
//     Gbf  [1024][16][32] @6422528
//     Wbf  [6912][32]     @6946816
#define WS_PARTIAL 0
#define WS_USHORT  7128
#define U_AMF  0
#define U_BPF  229376
#define U_GBF  6422528
#define U_WBF  6946816

#define JREG_BLOCKS 192                  // 24 joints x 8 chunks
#define JNT_BLOCKS  256                  // 1024/4 joints blocks in k_mid
#define BPF_BLOCKS  (NPROWS / 16)        // 1728
#define WBF_BLOCKS  (NVPAD * 32 / 256)   // 864

// ---------------- Kernel 1: jreg stage-1 partials only ----------------
__global__ __launch_bounds__(256)
void k_jreg(const float* __restrict__ Jreg,
            const float* __restrict__ shapedirs,
            const float* __restrict__ v_template,
            float* __restrict__ partial) {
    const int bid = blockIdx.x;
    const int tid = threadIdx.x;
    const int j = bid >> 3, chunk = bid & 7;
    const int per = (N_V + 7) / 8;
    const int v0 = chunk * per;
    const int v1 = (v0 + per < N_V) ? (v0 + per) : N_V;
    float acc[33];
#pragma unroll
    for (int k = 0; k < 33; ++k) acc[k] = 0.f;
    for (int v = v0 + tid; v < v1; v += 256) {
        const float w = Jreg[j * N_V + v];
        const float* sd = shapedirs + (size_t)v * 30;
#pragma unroll
        for (int k = 0; k < 30; ++k) acc[k] += w * sd[k];
        acc[30] += w * v_template[v * 3 + 0];
        acc[31] += w * v_template[v * 3 + 1];
        acc[32] += w * v_template[v * 3 + 2];
    }
#pragma unroll
    for (int k = 0; k < 33; ++k) {
        float x = acc[k];
        for (int off = 32; off > 0; off >>= 1) x += __shfl_down(x, off);
        acc[k] = x;
    }
    __shared__ float red[4][33];
    const int wave = tid >> 6, lane = tid & 63;
    if (lane == 0) {
#pragma unroll
        for (int k = 0; k < 33; ++k) red[wave][k] = acc[k];
    }
    __syncthreads();
    if (tid < 33) {
        partial[(j * 8 + chunk) * 33 + tid] =
            red[0][tid] + red[1][tid] + red[2][tid] + red[3][tid];
    }
}

// ---------------- Kernel 2: k_mid = joints(4/block) | Bpf | Wbf ----------------
__global__ __launch_bounds__(256)
void k_mid(const float* __restrict__ pose, const float* __restrict__ beta,
           const float* __restrict__ partial,
           const float* __restrict__ shapedirs,
           const float* __restrict__ v_template,
           const float* __restrict__ posedirs,
           const float* __restrict__ weights,
           unsigned short* __restrict__ Amf,
           unsigned short* __restrict__ Gbf,
           unsigned short* __restrict__ Bpf,
           unsigned short* __restrict__ Wbf) {
    const int bid = blockIdx.x;
    const int tid = threadIdx.x;

    if (bid < JNT_BLOCKS) {
        // ---- joints: 4 batches per block (verified R14 body) ----
        const int wid = tid >> 6;          // batch-in-block 0..3
        const int j = tid & 63;
        const int b = bid * 4 + wid;
        __shared__ float sJS[24][30];
        __shared__ float sJt_[24][3];
        __shared__ float sJ[4][24][3];
        __shared__ float sG[4][24][12];

        for (int idx = tid; idx < 792; idx += 256) {
            const int jj = idx / 33, kk = idx - jj * 33;
            float s = 0.f;
#pragma unroll
            for (int c = 0; c < 8; ++c) s += partial[(jj * 8 + c) * 33 + kk];
            if (kk < 30) sJS[jj][kk] = s;
            else         sJt_[jj][kk - 30] = s;
        }

        for (int idx = j; idx < 224; idx += 64) {
            int mn, jj;
            if (idx < 128) { mn = 12 + (idx >> 5); jj = idx & 31; }
            else { const int q = idx - 128; mn = q >> 3; jj = 24 + (q & 7); }
            Gbf[(size_t)b * 512 + mn * 32 + jj] = 0;
        }
        __syncthreads();

        float R[9];
        if (j < 24) {
            const float* bt = beta + b * 10;
#pragma unroll
            for (int c = 0; c < 3; ++c) {
                float s = sJt_[j][c];
#pragma unroll
                for (int t = 0; t < 10; ++t) s += sJS[j][c * 10 + t] * bt[t];
                sJ[wid][j][c] = s;
            }
            const float rx = pose[b * 72 + 3 * j + 0];
            const float ry = pose[b * 72 + 3 * j + 1];
            const float rz = pose[b * 72 + 3 * j + 2];
            const float ang = sqrtf(rx * rx + ry * ry + rz * rz + 1e-8f);
            const float inv = 1.f / ang;
            const float x = rx * inv, y = ry * inv, z = rz * inv;
            const float c = cosf(ang), s = sinf(ang);
            const float ic = 1.f - c;
            R[0] = c + ic * x * x;     R[1] = ic * x * y - s * z; R[2] = ic * x * z + s * y;
            R[3] = ic * x * y + s * z; R[4] = c + ic * y * y;     R[5] = ic * y * z - s * x;
            R[6] = ic * x * z - s * y; R[7] = ic * y * z + s * x; R[8] = c + ic * z * z;
            if (j >= 1) {
                const int kb = (j - 1) * 9;
#pragma unroll
                for (int k = 0; k < 9; ++k)
                    Amf[fragidx(b & 15, kb + k) + (size_t)(b >> 4) * 3584] =
                        f2bf(R[k] - ((k == 0 || k == 4 || k == 8) ? 1.f : 0.f));
            }
        } else if (j < 41) {
            const int k = 207 + (j - 24);
            float val = (k < 217) ? beta[b * 10 + (k - 207)] : (k == 217 ? 1.f : 0.f);
            Amf[fragidx(b & 15, k) + (size_t)(b >> 4) * 3584] = f2bf(val);
        }
        __syncthreads();
        if (j < 24) {
            float t0, t1, t2;
            if (j == 0) { t0 = sJ[wid][0][0]; t1 = sJ[wid][0][1]; t2 = sJ[wid][0][2]; }
            else {
                const int p = c_par[j - 1];
                t0 = sJ[wid][j][0] - sJ[wid][p][0];
                t1 = sJ[wid][j][1] - sJ[wid][p][1];
                t2 = sJ[wid][j][2] - sJ[wid][p][2];
            }
            sG[wid][j][0] = R[0]; sG[wid][j][1] = R[1]; sG[wid][j][2]  = R[2]; sG[wid][j][3]  = t0;
            sG[wid][j][4] = R[3]; sG[wid][j][5] = R[4]; sG[wid][j][6]  = R[5]; sG[wid][j][7]  = t1;
            sG[wid][j][8] = R[6]; sG[wid][j][9] = R[7]; sG[wid][j][10] = R[8]; sG[wid][j][11] = t2;
        }
        __syncthreads();
        if (j == 0) {
            for (int i = 1; i < 24; ++i) {
                const int p = c_par[i - 1];
                float P[12], L[12];
#pragma unroll
                for (int k = 0; k < 12; ++k) { P[k] = sG[wid][p][k]; L[k] = sG[wid][i][k]; }
#pragma unroll
                for (int m = 0; m < 3; ++m) {
#pragma unroll
                    for (int n = 0; n < 3; ++n)
                        sG[wid][i][m * 4 + n] = P[m * 4] * L[n] + P[m * 4 + 1] * L[4 + n] + P[m * 4 + 2] * L[8 + n];
                    sG[wid][i][m * 4 + 3] = P[m * 4] * L[3] + P[m * 4 + 1] * L[7] + P[m * 4 + 2] * L[11] + P[m * 4 + 3];
                }
            }
        }
        __syncthreads();
        if (j < 24) {
            const float jx = sJ[wid][j][0], jy = sJ[wid][j][1], jz = sJ[wid][j][2];
#pragma unroll
            for (int m = 0; m < 3; ++m) {
                const float corr = sG[wid][j][m * 4] * jx + sG[wid][j][m * 4 + 1] * jy + sG[wid][j][m * 4 + 2] * jz;
                Gbf[(size_t)b * 512 + (m * 4 + 0) * 32 + j] = f2bf(sG[wid][j][m * 4 + 0]);
                Gbf[(size_t)b * 512 + (m * 4 + 1) * 32 + j] = f2bf(sG[wid][j][m * 4 + 1]);
                Gbf[(size_t)b * 512 + (m * 4 + 2) * 32 + j] = f2bf(sG[wid][j][m * 4 + 2]);
                Gbf[(size_t)b * 512 + (m * 4 + 3) * 32 + j] = f2bf(sG[wid][j][m * 4 + 3] - corr);
            }
        }
    } else if (bid < JNT_BLOCKS + BPF_BLOCKS) {
        // ---- Bpf: stage [16][224] f32 tile in LDS, emit frag-linear (division-free) ----
        __shared__ float tile[16][228];
        const int r16 = bid - JNT_BLOCKS;
        {
            const int row = tid >> 4;          // 0..15
            const int k0 = (tid & 15) * 14;    // 14 consecutive k
            const int np = r16 * 16 + row;
            const int v = np >> 2, cc = np & 3;
            if (cc < 3 && v < N_V) {
                const int nc = v * 3 + cc;
                const float* pd = posedirs + (size_t)nc * 207;
#pragma unroll
                for (int i = 0; i < 14; ++i) {
                    const int k = k0 + i;
                    float val;
                    if (k < 207)       val = pd[k];
                    else if (k < 217)  val = shapedirs[(size_t)nc * 10 + (k - 207)];
                    else if (k == 217) val = v_template[nc];
                    else               val = 0.f;
                    tile[row][k] = val;
                }
            } else {
#pragma unroll
                for (int i = 0; i < 14; ++i) tile[row][k0 + i] = 0.f;
            }
        }
        __syncthreads();
        const int l = tid >> 2;
        const int row = l & 15;
        const int kblk = (l >> 4) * 8;
        const int e2 = (tid & 3) * 2;
        unsigned short* dst = Bpf + ((size_t)r16 * 7) * 512 + (size_t)tid * 2;
#pragma unroll
        for (int ks = 0; ks < 7; ++ks) {
            const int k = ks * 32 + kblk + e2;
            ushort2 o;
            o.x = f2bf(tile[row][k]);
            o.y = f2bf(tile[row][k + 1]);
            *(ushort2*)(dst + (size_t)ks * 512) = o;
        }
    } else {
        // ---- Wbf[v][32] bf16 zero-padded ----
        const int idx = (bid - JNT_BLOCKS - BPF_BLOCKS) * 256 + tid;
        const int v = idx >> 5, k = idx & 31;
        float val = (v < N_V && k < 24) ? weights[(size_t)v * 24 + k] : 0.f;
        Wbf[idx] = f2bf(val);
    }
}

// ---------------- Kernel 3: fused pose-GEMM + skinning (R16/R19 config, verbatim) ----
__global__ __launch_bounds__(512, 4)
void k_fused(const unsigned short* __restrict__ Amf,
             const unsigned short* __restrict__ Bpf,
             const unsigned short* __restrict__ Gbf,
             const unsigned short* __restrict__ Wbf,
             float* __restrict__ out) {
    __shared__ unsigned short sH[FB * SHP];   // 33,280 B  ([b][v][4] bf16)
    const int tid = threadIdx.x;
    const int wid = tid >> 6, l = tid & 63;   // wid 0..7
    const int c16 = l & 15, p = l >> 4;

    // bijective XCD swizzle for 1728 blocks: 1728 = 8 x 216
    const int wg = ((blockIdx.x & 7) * 216) + (blockIdx.x >> 3);
    const int xt = wg >> 4;    // vertex tile 0..107
    const int bg = wg & 15;    // batch group 0..15
    const int v0 = xt * FV;
    const int b0 = bg * FB;

    // phase-2 invariant loads issued first (latency hides under phase 1)
    bf16x8 bw[4];
#pragma unroll
    for (int g = 0; g < 4; ++g)
        bw[g] = *(const bf16x8*)&Wbf[(size_t)(v0 + g * 16 + c16) * 32 + p * 8];
    const int bwv = wid * 8;  // wave's local batch base
    const unsigned short* gG = Gbf + (size_t)(b0 + bwv) * 512 + c16 * 32 + p * 8;

    // -------- phase 1: register GEMM, frag-linear operands from global --------
    f32x4 acc[2][4];
#pragma unroll
    for (int i = 0; i < 2; ++i)
#pragma unroll
        for (int j = 0; j < 4; ++j) acc[i][j] = (f32x4){0.f, 0.f, 0.f, 0.f};

    const unsigned short* pbf = Bpf + ((size_t)(xt * 16 + wid * 2) * 7) * 512 + (size_t)l * 8;
    const unsigned short* pam = Amf + ((size_t)(bg * 4) * 7) * 512 + (size_t)l * 8;

#pragma unroll
    for (int ks = 0; ks < 7; ++ks) {
        bf16x8 af[2], bfr[4];
#pragma unroll
        for (int mi = 0; mi < 2; ++mi)
            af[mi] = *(const bf16x8*)(pbf + (size_t)(mi * 7 + ks) * 512);
#pragma unroll
        for (int bj = 0; bj < 4; ++bj)
            bfr[bj] = *(const bf16x8*)(pam + (size_t)(bj * 7 + ks) * 512);
        __builtin_amdgcn_s_setprio(1);
#pragma unroll
        for (int mi = 0; mi < 2; ++mi)
#pragma unroll
            for (int bj = 0; bj < 4; ++bj)
                acc[mi][bj] = __builtin_amdgcn_mfma_f32_16x16x32_bf16(af[mi], bfr[bj], acc[mi][bj], 0, 0, 0);
        __builtin_amdgcn_s_setprio(0);
    }

    // first Gbf chunk issued BEFORE epilogue: latency hides under ds_writes+barrier
    bf16x8 agA[4], agB[4];
#pragma unroll
    for (int j = 0; j < 4; ++j)
        agA[j] = *(const bf16x8*)(gG + (size_t)j * 512);

    // -------- epilogue: acc -> sH (b64 per vertex slot) --------
    {
        const int vbase = wid * 8 + p;
#pragma unroll
        for (int mi = 0; mi < 2; ++mi) {
#pragma unroll
            for (int bj = 0; bj < 4; ++bj) {
                const int vl = vbase + mi * 4;
                const int bl = bj * 16 + c16;
                uint2 u;
                u.x = pkbf(acc[mi][bj][0], acc[mi][bj][1]);
                u.y = pkbf(acc[mi][bj][2], acc[mi][bj][3]);
                *(uint2*)&sH[bl * SHP + vl * 4] = u;
            }
        }
    }
    __syncthreads();

    // second Gbf chunk: latency hides under chunk-A compute
#pragma unroll
    for (int j = 0; j < 4; ++j)
        agB[j] = *(const bf16x8*)(gG + (size_t)(4 + j) * 512);

    // -------- phase 2: skinning, 4 vertex groups per batch --------
    bool st[4];
#pragma unroll
    for (int g = 0; g < 4; ++g)
        st[g] = (v0 + g * 16 + c16 < N_V) && (p < 3);
    float* ob = out + (size_t)(b0 + bwv) * NREAL + (size_t)(v0 + c16) * 3 + p;
    const unsigned short* sh = &sH[bwv * SHP + c16 * 4];

    __builtin_amdgcn_s_setprio(1);
#pragma unroll
    for (int j = 0; j < 4; ++j) {
#pragma unroll
        for (int g = 0; g < 4; ++g) {
            const f32x4 t = __builtin_amdgcn_mfma_f32_16x16x32_bf16(agA[j], bw[g], (f32x4){0.f,0.f,0.f,0.f}, 0, 0, 0);
            const uint2 h = *(const uint2*)(sh + j * SHP + g * 64);
            const float x = __uint_as_float(h.x << 16);
            const float y = __uint_as_float(h.x & 0xffff0000u);
            const float z = __uint_as_float(h.y << 16);
            const float r = t[0] * x + t[1] * y + t[2] * z + t[3];
            if (st[g]) ob[(size_t)j * NREAL + g * 48] = r;
        }
    }
    __builtin_amdgcn_s_setprio(0);
#pragma unroll
    for (int j = 0; j < 4; ++j) {
#pragma unroll
        for (int g = 0; g < 4; ++g) {
            const f32x4 t = __builtin_amdgcn_mfma_f32_16x16x32_bf16(agB[j], bw[g], (f32x4){0.f,0.f,0.f,0.f}, 0, 0, 0);
            const uint2 h = *(const uint2*)(sh + (4 + j) * SHP + g * 64);
            const float x = __uint_as_float(h.x << 16);
            const float y = __uint_as_float(h.x & 0xffff0000u);
            const float z = __uint_as_float(h.y << 16);
            const float r = t[0] * x + t[1] * y + t[2] * z + t[3];
            if (st[g]) ob[(size_t)(4 + j) * NREAL + g * 48] = r;
        }
    }
}

extern "C" void kernel_launch(void* const* d_in, const int* in_sizes, int n_in,
                              void* d_out, int out_size, void* d_ws, size_t ws_size,
                              hipStream_t stream) {
    const float* pose       = (const float*)d_in[0];
    const float* beta       = (const float*)d_in[1];
    const float* shapedirs  = (const float*)d_in[2];
    const float* posedirs   = (const float*)d_in[3];
    const float* v_template = (const float*)d_in[4];
    const float* Jreg       = (const float*)d_in[5];
    const float* weights    = (const float*)d_in[6];
    float* out = (float*)d_out;

    const int B = in_sizes[0] / 72;  // 1024

    float* ws = (float*)d_ws;
    float* partial = ws + WS_PARTIAL;
    unsigned short* ubase = (unsigned short*)(ws + WS_USHORT);
    unsigned short* Amf = ubase + U_AMF;
    unsigned short* Bpf = ubase + U_BPF;
    unsigned short* Gbf = ubase + U_GBF;
    unsigned short* Wbf = ubase + U_WBF;

    k_jreg<<<JREG_BLOCKS, 256, 0, stream>>>(Jreg, shapedirs, v_template, partial);
    k_mid<<<JNT_BLOCKS + BPF_BLOCKS + WBF_BLOCKS, 256, 0, stream>>>(
        pose, beta, partial, shapedirs, v_template, posedirs, weights,
        Amf, Gbf, Bpf, Wbf);
    k_fused<<<NXT * (B / FB), 512, 0, stream>>>(Amf, Bpf, Gbf, Wbf, out);
}